// Round 13
// baseline (417.913 us; speedup 1.0000x reference)
//
#include <hip/hip_runtime.h>
#include <hip/hip_bf16.h>

// SageNet: 4-layer GraphSAGE (mean aggr), N=100000 nodes, E=600000 edges.
// DIMS: 128 -> 64 -> 32 -> 16 -> 9.
//
// agg(x) @ w_l == agg(x @ w_l)  (mean aggregation is linear), so per layer:
//   lin:  y = x @ wl ; z = x @ wr + b
//   agg:  out[n] = act(z[n] + (sum_{in-edges} y[src]) * inv_deg[n])
// Pull-style CSR aggregation (built on device), zero float atomics.
//
// R6-R8: lin0 ~86-96us, VALUBusy ~26% = latency-stalled at ~12 waves/CU.
// R12: register-staged prefetch REGRESSED (110us): WRITE 54->97MB, FETCH
//   27->43MB = scratch spills. VGPR_Count=64 everywhere: no launch_bounds
//   -> hipcc caps at 64 VGPR (1024-thr default) with a 64-reg accumulator.
// R13 fix: __launch_bounds__ lifts the cap; staging via global_load_lds
//   width=16 (zero VGPR cost) into LINEAR row-major LDS (wave-uniform base
//   + lane*16), double-buffered: STAGE(next) -> compute(cur) -> barrier,
//   so the pre-barrier vmcnt(0) drain lands after ~2600cy of FMAs.

#define BLK 256

#define GLOAD_LDS16(gptr, lptr)                                              \
    __builtin_amdgcn_global_load_lds(                                        \
        (const __attribute__((address_space(1))) void*)(gptr),               \
        (__attribute__((address_space(3))) void*)(lptr), 16, 0, 0)

// ---------------- CSR build ----------------

__global__ void hist_kernel(const int* __restrict__ dst, int* __restrict__ deg, int e) {
    int t = blockIdx.x * blockDim.x + threadIdx.x;
    if (t < e) atomicAdd(&deg[dst[t]], 1);
}

__global__ void scan1_kernel(const int* __restrict__ deg, int* __restrict__ excl,
                             int* __restrict__ bsums, int n) {
    __shared__ int sm[256];
    int base = blockIdx.x * 1024;
    int t = threadIdx.x;
    int v[4];
    int s = 0;
    #pragma unroll
    for (int j = 0; j < 4; j++) {
        int i = base + t * 4 + j;
        v[j] = (i < n) ? deg[i] : 0;
        s += v[j];
    }
    sm[t] = s;
    __syncthreads();
    for (int off = 1; off < 256; off <<= 1) {
        int x = (t >= off) ? sm[t - off] : 0;
        __syncthreads();
        sm[t] += x;
        __syncthreads();
    }
    int excl_t = sm[t] - s;
    if (t == 255) bsums[blockIdx.x] = sm[255];
    int run = excl_t;
    #pragma unroll
    for (int j = 0; j < 4; j++) {
        int i = base + t * 4 + j;
        if (i < n) excl[i] = run;
        run += v[j];
    }
}

__global__ void scan2_kernel(int* __restrict__ bsums, int nb) {
    __shared__ int sm[256];
    int t = threadIdx.x;
    int v = (t < nb) ? bsums[t] : 0;
    sm[t] = v;
    __syncthreads();
    for (int off = 1; off < 256; off <<= 1) {
        int x = (t >= off) ? sm[t - off] : 0;
        __syncthreads();
        sm[t] += x;
        __syncthreads();
    }
    if (t < nb) bsums[t] = sm[t] - v;
}

__global__ void scan3_kernel(const int* __restrict__ deg, int* __restrict__ row_start,
                             const int* __restrict__ bsums, int* __restrict__ cursor,
                             float* __restrict__ inv_deg, int n, int e) {
    int t = blockIdx.x * blockDim.x + threadIdx.x;
    if (t < n) {
        int rs = row_start[t] + bsums[t >> 10];
        row_start[t] = rs;
        cursor[t] = rs;
        int d = deg[t];
        inv_deg[t] = 1.0f / (float)(d > 1 ? d : 1);
    }
    if (t == 0) row_start[n] = e;
}

__global__ void scatter_kernel(const int* __restrict__ src, const int* __restrict__ dst,
                               int* __restrict__ cursor, int* __restrict__ ssrc, int e) {
    int t = blockIdx.x * blockDim.x + threadIdx.x;
    if (t < e) {
        int p = atomicAdd(&cursor[dst[t]], 1);
        ssrc[p] = src[t];
    }
}

// ---------------- tiled dual-GEMM lin via global_load_lds dbuf ----------------
// x tile ROW-MAJOR [BM][KC] in LDS (linear: gload_lds dest = wave-uniform
// base + lane*16). Weights from global (L2-resident, block-wide reuse).
// TN fixed at 4.

template <int FIN, int FOUT, int BM, int KC, int TM, int THREADS>
__global__ __launch_bounds__(THREADS, 1)
void lin_glds(const float* __restrict__ x, const float* __restrict__ wl,
              const float* __restrict__ wr, const float* __restrict__ b,
              float* __restrict__ y, float* __restrict__ z, int n) {
    constexpr int TN = 4;
    constexpr int CPR = FOUT / TN;                // threads along f (float4 per w-row)
    static_assert(THREADS == (BM / TM) * CPR, "thread shape mismatch");
    constexpr int SLOTS = BM * KC / 4;            // float4 slots per buffer
    constexpr int LPT = SLOTS / THREADS;          // gload_lds issues per thread
    constexpr int SPR = KC / 4;                   // float4 slots per x row
    constexpr int NCH = FIN / KC;
    __shared__ float xs[2][BM * KC];

    const int tid = threadIdx.x;
    const int wave = tid >> 6;
    const int r = tid / CPR;
    const int c = tid % CPR;
    const int m0 = r * TM;
    const int nodeBase = blockIdx.x * BM;
    const float4* wl4 = (const float4*)wl;
    const float4* wr4 = (const float4*)wr;

    auto stage = [&](int buf, int ch) {
        #pragma unroll
        for (int l = 0; l < LPT; l++) {
            int s = l * THREADS + tid;            // this lane's slot
            int node = s / SPR;
            int kq = s % SPR;
            const float* g = x + (size_t)(nodeBase + node) * FIN + ch * KC + kq * 4;
            // wave-uniform LDS base; HW adds lane*16
            float* lbase = &xs[buf][(size_t)(l * THREADS + wave * 64) * 4];
            if (nodeBase + node < n) GLOAD_LDS16(g, lbase);
        }
    };

    stage(0, 0);

    float accy[TM][TN] = {};
    float accz[TM][TN] = {};

    __syncthreads();                               // waits chunk-0 vmcnt
    for (int ch = 0; ch < NCH; ch++) {
        const int cur = ch & 1;
        if (ch + 1 < NCH) stage(cur ^ 1, ch + 1);  // in flight during compute
        #pragma unroll
        for (int k4 = 0; k4 < KC / 4; k4++) {
            float4 a4[TM];
            #pragma unroll
            for (int i = 0; i < TM; i++)
                a4[i] = *(const float4*)&xs[cur][(m0 + i) * KC + k4 * 4];
            #pragma unroll
            for (int kk = 0; kk < 4; kk++) {
                int k = ch * KC + k4 * 4 + kk;
                float4 blv = wl4[(size_t)k * CPR + c];
                float4 brv = wr4[(size_t)k * CPR + c];
                #pragma unroll
                for (int i = 0; i < TM; i++) {
                    float av = ((const float*)&a4[i])[kk];   // static after unroll
                    accy[i][0] = fmaf(av, blv.x, accy[i][0]);
                    accy[i][1] = fmaf(av, blv.y, accy[i][1]);
                    accy[i][2] = fmaf(av, blv.z, accy[i][2]);
                    accy[i][3] = fmaf(av, blv.w, accy[i][3]);
                    accz[i][0] = fmaf(av, brv.x, accz[i][0]);
                    accz[i][1] = fmaf(av, brv.y, accz[i][1]);
                    accz[i][2] = fmaf(av, brv.z, accz[i][2]);
                    accz[i][3] = fmaf(av, brv.w, accz[i][3]);
                }
            }
        }
        __syncthreads();   // vmcnt drain lands after ~KC*TM*8 FMA cycles
    }

    float4 bv = *(const float4*)(b + c * 4);
    #pragma unroll
    for (int i = 0; i < TM; i++) {
        int gn = nodeBase + m0 + i;
        if (gn < n) {
            float4 vy = {accy[i][0], accy[i][1], accy[i][2], accy[i][3]};
            float4 vz = {accz[i][0] + bv.x, accz[i][1] + bv.y,
                         accz[i][2] + bv.z, accz[i][3] + bv.w};
            *(float4*)(y + (size_t)gn * FOUT + c * 4) = vy;
            *(float4*)(z + (size_t)gn * FOUT + c * 4) = vz;
        }
    }
}

// naive per-node lin for the tiny layers (2: 32->16, 3: 16->9).
template <int FIN, int FOUT>
__global__ void lin_naive(const float* __restrict__ x, const float* __restrict__ wl,
                          const float* __restrict__ wr, const float* __restrict__ b,
                          float* __restrict__ y, float* __restrict__ z, int n) {
    int t = blockIdx.x * blockDim.x + threadIdx.x;
    int node = t / FOUT;
    int f = t % FOUT;
    if (node >= n) return;
    const float* xr = x + (size_t)node * FIN;
    float accy = 0.f, accz = 0.f;
    #pragma unroll
    for (int k = 0; k < FIN; k++) {
        float xv = xr[k];
        accy = fmaf(xv, wl[k * FOUT + f], accy);
        accz = fmaf(xv, wr[k * FOUT + f], accz);
    }
    y[(size_t)node * FOUT + f] = accy;
    z[(size_t)node * FOUT + f] = accz + b[f];
}

// ---------------- aggregation (4-deep gather ILP) ----------------

template <int FOUT, bool RELU>
__global__ void agg4_kernel(const float4* __restrict__ y4, const int* __restrict__ row_start,
                            const int* __restrict__ ssrc, const float* __restrict__ inv_deg,
                            float4* __restrict__ out4, int n) {
    constexpr int Q = FOUT / 4;
    int t = blockIdx.x * blockDim.x + threadIdx.x;
    int node = t / Q;
    int q = t % Q;
    if (node >= n) return;
    int e0 = row_start[node];
    int e1 = row_start[node + 1];
    float4 s = {0.f, 0.f, 0.f, 0.f};
    int e = e0;
    for (; e + 3 < e1; e += 4) {
        int sn0 = ssrc[e];
        int sn1 = ssrc[e + 1];
        int sn2 = ssrc[e + 2];
        int sn3 = ssrc[e + 3];
        float4 v0 = y4[(size_t)sn0 * Q + q];
        float4 v1 = y4[(size_t)sn1 * Q + q];
        float4 v2 = y4[(size_t)sn2 * Q + q];
        float4 v3 = y4[(size_t)sn3 * Q + q];
        s.x += v0.x + v1.x + v2.x + v3.x;
        s.y += v0.y + v1.y + v2.y + v3.y;
        s.z += v0.z + v1.z + v2.z + v3.z;
        s.w += v0.w + v1.w + v2.w + v3.w;
    }
    if (e + 1 < e1) {
        int sn0 = ssrc[e];
        int sn1 = ssrc[e + 1];
        float4 v0 = y4[(size_t)sn0 * Q + q];
        float4 v1 = y4[(size_t)sn1 * Q + q];
        s.x += v0.x + v1.x; s.y += v0.y + v1.y;
        s.z += v0.z + v1.z; s.w += v0.w + v1.w;
        e += 2;
    }
    if (e < e1) {
        int sn = ssrc[e];
        float4 v = y4[(size_t)sn * Q + q];
        s.x += v.x; s.y += v.y; s.z += v.z; s.w += v.w;
    }
    float id = inv_deg[node];
    float4 o = out4[(size_t)node * Q + q];
    o.x += s.x * id; o.y += s.y * id; o.z += s.z * id; o.w += s.w * id;
    if (RELU) {
        o.x = fmaxf(o.x, 0.f); o.y = fmaxf(o.y, 0.f);
        o.z = fmaxf(o.z, 0.f); o.w = fmaxf(o.w, 0.f);
    }
    out4[(size_t)node * Q + q] = o;
}

template <int FOUT, bool RELU>
__global__ void agg_kernel(const float* __restrict__ y, const int* __restrict__ row_start,
                           const int* __restrict__ ssrc, const float* __restrict__ inv_deg,
                           float* __restrict__ out, int n) {
    int t = blockIdx.x * blockDim.x + threadIdx.x;
    int node = t / FOUT;
    int f = t % FOUT;
    if (node >= n) return;
    int e0 = row_start[node];
    int e1 = row_start[node + 1];
    float s = 0.f;
    int e = e0;
    for (; e + 3 < e1; e += 4) {
        int sn0 = ssrc[e];
        int sn1 = ssrc[e + 1];
        int sn2 = ssrc[e + 2];
        int sn3 = ssrc[e + 3];
        float v0 = y[(size_t)sn0 * FOUT + f];
        float v1 = y[(size_t)sn1 * FOUT + f];
        float v2 = y[(size_t)sn2 * FOUT + f];
        float v3 = y[(size_t)sn3 * FOUT + f];
        s += (v0 + v1) + (v2 + v3);
    }
    for (; e < e1; e++) s += y[(size_t)ssrc[e] * FOUT + f];
    float v = out[(size_t)node * FOUT + f] + s * inv_deg[node];
    if (RELU) v = fmaxf(v, 0.f);
    out[(size_t)node * FOUT + f] = v;
}

// ---------------- launch ----------------

static inline int cdiv(int a, int b) { return (a + b - 1) / b; }

extern "C" void kernel_launch(void* const* d_in, const int* in_sizes, int n_in,
                              void* d_out, int out_size, void* d_ws, size_t ws_size,
                              hipStream_t stream) {
    const float* emb  = (const float*)d_in[0];
    const int*   eidx = (const int*)d_in[1];
    const float* wl0 = (const float*)d_in[3];
    const float* wr0 = (const float*)d_in[4];
    const float* b0  = (const float*)d_in[5];
    const float* wl1 = (const float*)d_in[6];
    const float* wr1 = (const float*)d_in[7];
    const float* b1  = (const float*)d_in[8];
    const float* wl2 = (const float*)d_in[9];
    const float* wr2 = (const float*)d_in[10];
    const float* b2  = (const float*)d_in[11];
    const float* wl3 = (const float*)d_in[12];
    const float* wr3 = (const float*)d_in[13];
    const float* b3  = (const float*)d_in[14];

    const int n = in_sizes[0] / 128;   // 100000
    const int e = in_sizes[1] / 2;     // 600000
    const int* src = eidx;
    const int* dst = eidx + e;

    char* ws = (char*)d_ws;
    size_t off = 0;
    auto alloc = [&](size_t bytes) -> void* {
        void* p = ws + off;
        off = (off + bytes + 255) & ~(size_t)255;
        return p;
    };
    int*   deg       = (int*)alloc((size_t)n * 4);
    float* inv_deg   = (float*)alloc((size_t)n * 4);
    int*   row_start = (int*)alloc(((size_t)n + 1) * 4);
    int*   cursor    = (int*)alloc((size_t)n * 4);
    int*   bsums     = (int*)alloc(1024 * 4);
    int*   ssrc      = (int*)alloc((size_t)e * 4);
    float* Y         = (float*)alloc((size_t)n * 64 * 4);
    float* xA        = (float*)alloc((size_t)n * 64 * 4);
    float* xB        = (float*)alloc((size_t)n * 32 * 4);
    (void)ws_size;

    // ---- CSR build ----
    hipMemsetAsync(deg, 0, (size_t)n * 4, stream);
    hist_kernel<<<cdiv(e, BLK), BLK, 0, stream>>>(dst, deg, e);
    int nchunks = cdiv(n, 1024);
    scan1_kernel<<<nchunks, 256, 0, stream>>>(deg, row_start, bsums, n);
    scan2_kernel<<<1, 256, 0, stream>>>(bsums, nchunks);
    scan3_kernel<<<cdiv(n, BLK), BLK, 0, stream>>>(deg, row_start, bsums, cursor, inv_deg, n, e);
    scatter_kernel<<<cdiv(e, BLK), BLK, 0, stream>>>(src, dst, cursor, ssrc, e);

    float* out = (float*)d_out;

    // ---- layer 0: 128 -> 64, relu ----  BM=128, TM=8, 256 thr, 32KB LDS dbuf
    lin_glds<128, 64, 128, 32, 8, 256><<<cdiv(n, 128), 256, 0, stream>>>(emb, wl0, wr0, b0, Y, xA, n);
    agg4_kernel<64, true><<<cdiv(n * 16, BLK), BLK, 0, stream>>>((const float4*)Y, row_start, ssrc, inv_deg, (float4*)xA, n);

    // ---- layer 1: 64 -> 32, relu ----  BM=128, TM=4, 256 thr
    lin_glds<64, 32, 128, 32, 4, 256><<<cdiv(n, 128), 256, 0, stream>>>(xA, wl1, wr1, b1, Y, xB, n);
    agg4_kernel<32, true><<<cdiv(n * 8, BLK), BLK, 0, stream>>>((const float4*)Y, row_start, ssrc, inv_deg, (float4*)xB, n);

    // ---- layer 2: 32 -> 16, relu ----  naive (R1-measured class)
    lin_naive<32, 16><<<cdiv(n * 16, BLK), BLK, 0, stream>>>(xB, wl2, wr2, b2, Y, xA, n);
    agg4_kernel<16, true><<<cdiv(n * 4, BLK), BLK, 0, stream>>>((const float4*)Y, row_start, ssrc, inv_deg, (float4*)xA, n);

    // ---- layer 3: 16 -> 9, no relu ----
    lin_naive<16, 9><<<cdiv(n * 9, BLK), BLK, 0, stream>>>(xA, wl3, wr3, b3, Y, out, n);
    agg_kernel<9, false><<<cdiv(n * 9, BLK), BLK, 0, stream>>>(Y, row_start, ssrc, inv_deg, out, n);
}

// Round 15
// 397.333 us; speedup vs baseline: 1.0518x; 1.0518x over previous
//
#include <hip/hip_runtime.h>
#include <hip/hip_bf16.h>

// SageNet: 4-layer GraphSAGE (mean aggr), N=100000 nodes, E=600000 edges.
// DIMS: 128 -> 64 -> 32 -> 16 -> 9.
//
// agg(x) @ w_l == agg(x @ w_l)  (mean aggregation is linear), so per layer:
//   lin:  y = x @ wl ; z = x @ wr + b
//   agg:  out[n] = act(z[n] + (sum_{in-edges} y[src]) * inv_deg[n])
// Pull-style CSR aggregation (built on device), zero float atomics.
//
// Ledger: R8 best lin0 = 86us (transposed xT, conflict-free reads, VALUBusy
//   26% = latency at chunk barriers). R12 reg-prefetch spilled (no
//   launch_bounds, VGPR capped 64 -> scratch, WRITE 54->97MB). R13
//   global_load_lds row-major tile = 32-way read conflicts (3.2M) + 32KB
//   LDS occupancy drop -> 130us. R14 = R8 layout + R12 reorder + bounds:
//   ds_write(ch) -> barrier -> issue loads(ch+1) [ptr-bump, clamped rows]
//   -> compute(ch) -> barrier. launch_bounds(,2) => VGPR cap 256, no spill.

#define BLK 256

// ---------------- CSR build ----------------

__global__ void hist_kernel(const int* __restrict__ dst, int* __restrict__ deg, int e) {
    int t = blockIdx.x * blockDim.x + threadIdx.x;
    if (t < e) atomicAdd(&deg[dst[t]], 1);
}

__global__ void scan1_kernel(const int* __restrict__ deg, int* __restrict__ excl,
                             int* __restrict__ bsums, int n) {
    __shared__ int sm[256];
    int base = blockIdx.x * 1024;
    int t = threadIdx.x;
    int v[4];
    int s = 0;
    #pragma unroll
    for (int j = 0; j < 4; j++) {
        int i = base + t * 4 + j;
        v[j] = (i < n) ? deg[i] : 0;
        s += v[j];
    }
    sm[t] = s;
    __syncthreads();
    for (int off = 1; off < 256; off <<= 1) {
        int x = (t >= off) ? sm[t - off] : 0;
        __syncthreads();
        sm[t] += x;
        __syncthreads();
    }
    int excl_t = sm[t] - s;
    if (t == 255) bsums[blockIdx.x] = sm[255];
    int run = excl_t;
    #pragma unroll
    for (int j = 0; j < 4; j++) {
        int i = base + t * 4 + j;
        if (i < n) excl[i] = run;
        run += v[j];
    }
}

__global__ void scan2_kernel(int* __restrict__ bsums, int nb) {
    __shared__ int sm[256];
    int t = threadIdx.x;
    int v = (t < nb) ? bsums[t] : 0;
    sm[t] = v;
    __syncthreads();
    for (int off = 1; off < 256; off <<= 1) {
        int x = (t >= off) ? sm[t - off] : 0;
        __syncthreads();
        sm[t] += x;
        __syncthreads();
    }
    if (t < nb) bsums[t] = sm[t] - v;
}

__global__ void scan3_kernel(const int* __restrict__ deg, int* __restrict__ row_start,
                             const int* __restrict__ bsums, int* __restrict__ cursor,
                             float* __restrict__ inv_deg, int n, int e) {
    int t = blockIdx.x * blockDim.x + threadIdx.x;
    if (t < n) {
        int rs = row_start[t] + bsums[t >> 10];
        row_start[t] = rs;
        cursor[t] = rs;
        int d = deg[t];
        inv_deg[t] = 1.0f / (float)(d > 1 ? d : 1);
    }
    if (t == 0) row_start[n] = e;
}

__global__ void scatter_kernel(const int* __restrict__ src, const int* __restrict__ dst,
                               int* __restrict__ cursor, int* __restrict__ ssrc, int e) {
    int t = blockIdx.x * blockDim.x + threadIdx.x;
    if (t < e) {
        int p = atomicAdd(&cursor[dst[t]], 1);
        ssrc[p] = src[t];
    }
}

// ---------------- tiled dual-GEMM lin, reg-prefetch + transposed LDS ----------------
// Per chunk: ds_write staged regs -> barrier -> issue next chunk loads
// (pointer bump) -> compute -> barrier. Weights from global (L2-resident).

template <int FIN, int FOUT, int BM, int KC, int TM, int TN, int THREADS>
__global__ __launch_bounds__(THREADS, 2)
void lin_tiled4(const float* __restrict__ x, const float* __restrict__ wl,
                const float* __restrict__ wr, const float* __restrict__ b,
                float* __restrict__ y, float* __restrict__ z, int n) {
    constexpr int PAD = 4;
    constexpr int CPR = FOUT / TN;                  // threads along f
    constexpr int XLOADS = (BM * KC) / (THREADS * 4);
    constexpr int NCH = FIN / KC;
    static_assert(THREADS == (BM / TM) * CPR, "thread shape mismatch");
    __shared__ float xT[KC][BM + PAD];

    const int tid = threadIdx.x;
    const int r = tid / CPR;
    const int c = tid % CPR;
    const int m0 = r * TM;
    const int f0 = c * TN;
    const int nodeBase = blockIdx.x * BM;

    // staging slots: clamped row => no per-load branch; OOB rows only feed
    // OOB outputs (write-guarded in epilogue)
    const float* gp[XLOADS];
    int nodeIdx[XLOADS], kkIdx[XLOADS];
    #pragma unroll
    for (int l = 0; l < XLOADS; l++) {
        int idx = (l * THREADS + tid) * 4;
        nodeIdx[l] = idx / KC;
        kkIdx[l] = idx % KC;
        int gn = nodeBase + nodeIdx[l];
        if (gn >= n) gn = n - 1;
        gp[l] = x + (size_t)gn * FIN + kkIdx[l];
    }

    float4 xreg[XLOADS];
    #pragma unroll
    for (int l = 0; l < XLOADS; l++) xreg[l] = *(const float4*)gp[l];   // chunk 0

    float accy[TM][TN] = {};
    float accz[TM][TN] = {};

    for (int ch = 0; ch < NCH; ch++) {
        #pragma unroll
        for (int l = 0; l < XLOADS; l++) {
            xT[kkIdx[l] + 0][nodeIdx[l]] = xreg[l].x;
            xT[kkIdx[l] + 1][nodeIdx[l]] = xreg[l].y;
            xT[kkIdx[l] + 2][nodeIdx[l]] = xreg[l].z;
            xT[kkIdx[l] + 3][nodeIdx[l]] = xreg[l].w;
        }
        __syncthreads();
        if (ch + 1 < NCH) {
            #pragma unroll
            for (int l = 0; l < XLOADS; l++)
                xreg[l] = *(const float4*)(gp[l] + (ch + 1) * KC);   // fly during compute
        }
        const int k0 = ch * KC;
        #pragma unroll 8
        for (int k = 0; k < KC; k++) {
            float a[TM];
            #pragma unroll
            for (int i = 0; i < TM; i += 4) *(float4*)&a[i] = *(const float4*)&xT[k][m0 + i];
            float4 blv = *(const float4*)(wl + (size_t)(k0 + k) * FOUT + f0);
            float4 brv = *(const float4*)(wr + (size_t)(k0 + k) * FOUT + f0);
            float bl[4] = {blv.x, blv.y, blv.z, blv.w};
            float br[4] = {brv.x, brv.y, brv.z, brv.w};
            #pragma unroll
            for (int i = 0; i < TM; i++)
                #pragma unroll
                for (int j = 0; j < TN; j++) {
                    accy[i][j] = fmaf(a[i], bl[j], accy[i][j]);
                    accz[i][j] = fmaf(a[i], br[j], accz[i][j]);
                }
        }
        __syncthreads();   // vmcnt drain lands after ~4096cy of FMAs
    }

    float4 bv = *(const float4*)(b + f0);
    float bias[4] = {bv.x, bv.y, bv.z, bv.w};
    #pragma unroll
    for (int i = 0; i < TM; i++) {
        int gn = nodeBase + m0 + i;
        if (gn < n) {
            #pragma unroll
            for (int j = 0; j < TN; j += 4) {
                float4 vy = {accy[i][j], accy[i][j+1], accy[i][j+2], accy[i][j+3]};
                float4 vz = {accz[i][j] + bias[j], accz[i][j+1] + bias[j+1],
                             accz[i][j+2] + bias[j+2], accz[i][j+3] + bias[j+3]};
                *(float4*)(y + (size_t)gn * FOUT + f0 + j) = vy;
                *(float4*)(z + (size_t)gn * FOUT + f0 + j) = vz;
            }
        }
    }
}

// naive per-node lin for the tiny layers (2: 32->16, 3: 16->9).
template <int FIN, int FOUT>
__global__ void lin_naive(const float* __restrict__ x, const float* __restrict__ wl,
                          const float* __restrict__ wr, const float* __restrict__ b,
                          float* __restrict__ y, float* __restrict__ z, int n) {
    int t = blockIdx.x * blockDim.x + threadIdx.x;
    int node = t / FOUT;
    int f = t % FOUT;
    if (node >= n) return;
    const float* xr = x + (size_t)node * FIN;
    float accy = 0.f, accz = 0.f;
    #pragma unroll
    for (int k = 0; k < FIN; k++) {
        float xv = xr[k];
        accy = fmaf(xv, wl[k * FOUT + f], accy);
        accz = fmaf(xv, wr[k * FOUT + f], accz);
    }
    y[(size_t)node * FOUT + f] = accy;
    z[(size_t)node * FOUT + f] = accz + b[f];
}

// ---------------- aggregation (4-deep gather ILP) ----------------

template <int FOUT, bool RELU>
__global__ void agg4_kernel(const float4* __restrict__ y4, const int* __restrict__ row_start,
                            const int* __restrict__ ssrc, const float* __restrict__ inv_deg,
                            float4* __restrict__ out4, int n) {
    constexpr int Q = FOUT / 4;
    int t = blockIdx.x * blockDim.x + threadIdx.x;
    int node = t / Q;
    int q = t % Q;
    if (node >= n) return;
    int e0 = row_start[node];
    int e1 = row_start[node + 1];
    float4 s = {0.f, 0.f, 0.f, 0.f};
    int e = e0;
    for (; e + 3 < e1; e += 4) {
        int sn0 = ssrc[e];
        int sn1 = ssrc[e + 1];
        int sn2 = ssrc[e + 2];
        int sn3 = ssrc[e + 3];
        float4 v0 = y4[(size_t)sn0 * Q + q];
        float4 v1 = y4[(size_t)sn1 * Q + q];
        float4 v2 = y4[(size_t)sn2 * Q + q];
        float4 v3 = y4[(size_t)sn3 * Q + q];
        s.x += v0.x + v1.x + v2.x + v3.x;
        s.y += v0.y + v1.y + v2.y + v3.y;
        s.z += v0.z + v1.z + v2.z + v3.z;
        s.w += v0.w + v1.w + v2.w + v3.w;
    }
    if (e + 1 < e1) {
        int sn0 = ssrc[e];
        int sn1 = ssrc[e + 1];
        float4 v0 = y4[(size_t)sn0 * Q + q];
        float4 v1 = y4[(size_t)sn1 * Q + q];
        s.x += v0.x + v1.x; s.y += v0.y + v1.y;
        s.z += v0.z + v1.z; s.w += v0.w + v1.w;
        e += 2;
    }
    if (e < e1) {
        int sn = ssrc[e];
        float4 v = y4[(size_t)sn * Q + q];
        s.x += v.x; s.y += v.y; s.z += v.z; s.w += v.w;
    }
    float id = inv_deg[node];
    float4 o = out4[(size_t)node * Q + q];
    o.x += s.x * id; o.y += s.y * id; o.z += s.z * id; o.w += s.w * id;
    if (RELU) {
        o.x = fmaxf(o.x, 0.f); o.y = fmaxf(o.y, 0.f);
        o.z = fmaxf(o.z, 0.f); o.w = fmaxf(o.w, 0.f);
    }
    out4[(size_t)node * Q + q] = o;
}

template <int FOUT, bool RELU>
__global__ void agg_kernel(const float* __restrict__ y, const int* __restrict__ row_start,
                           const int* __restrict__ ssrc, const float* __restrict__ inv_deg,
                           float* __restrict__ out, int n) {
    int t = blockIdx.x * blockDim.x + threadIdx.x;
    int node = t / FOUT;
    int f = t % FOUT;
    if (node >= n) return;
    int e0 = row_start[node];
    int e1 = row_start[node + 1];
    float s = 0.f;
    int e = e0;
    for (; e + 3 < e1; e += 4) {
        int sn0 = ssrc[e];
        int sn1 = ssrc[e + 1];
        int sn2 = ssrc[e + 2];
        int sn3 = ssrc[e + 3];
        float v0 = y[(size_t)sn0 * FOUT + f];
        float v1 = y[(size_t)sn1 * FOUT + f];
        float v2 = y[(size_t)sn2 * FOUT + f];
        float v3 = y[(size_t)sn3 * FOUT + f];
        s += (v0 + v1) + (v2 + v3);
    }
    for (; e < e1; e++) s += y[(size_t)ssrc[e] * FOUT + f];
    float v = out[(size_t)node * FOUT + f] + s * inv_deg[node];
    if (RELU) v = fmaxf(v, 0.f);
    out[(size_t)node * FOUT + f] = v;
}

// ---------------- launch ----------------

static inline int cdiv(int a, int b) { return (a + b - 1) / b; }

extern "C" void kernel_launch(void* const* d_in, const int* in_sizes, int n_in,
                              void* d_out, int out_size, void* d_ws, size_t ws_size,
                              hipStream_t stream) {
    const float* emb  = (const float*)d_in[0];
    const int*   eidx = (const int*)d_in[1];
    const float* wl0 = (const float*)d_in[3];
    const float* wr0 = (const float*)d_in[4];
    const float* b0  = (const float*)d_in[5];
    const float* wl1 = (const float*)d_in[6];
    const float* wr1 = (const float*)d_in[7];
    const float* b1  = (const float*)d_in[8];
    const float* wl2 = (const float*)d_in[9];
    const float* wr2 = (const float*)d_in[10];
    const float* b2  = (const float*)d_in[11];
    const float* wl3 = (const float*)d_in[12];
    const float* wr3 = (const float*)d_in[13];
    const float* b3  = (const float*)d_in[14];

    const int n = in_sizes[0] / 128;   // 100000
    const int e = in_sizes[1] / 2;     // 600000
    const int* src = eidx;
    const int* dst = eidx + e;

    char* ws = (char*)d_ws;
    size_t off = 0;
    auto alloc = [&](size_t bytes) -> void* {
        void* p = ws + off;
        off = (off + bytes + 255) & ~(size_t)255;
        return p;
    };
    int*   deg       = (int*)alloc((size_t)n * 4);
    float* inv_deg   = (float*)alloc((size_t)n * 4);
    int*   row_start = (int*)alloc(((size_t)n + 1) * 4);
    int*   cursor    = (int*)alloc((size_t)n * 4);
    int*   bsums     = (int*)alloc(1024 * 4);
    int*   ssrc      = (int*)alloc((size_t)e * 4);
    float* Y         = (float*)alloc((size_t)n * 64 * 4);
    float* xA        = (float*)alloc((size_t)n * 64 * 4);
    float* xB        = (float*)alloc((size_t)n * 32 * 4);
    (void)ws_size;

    // ---- CSR build ----
    hipMemsetAsync(deg, 0, (size_t)n * 4, stream);
    hist_kernel<<<cdiv(e, BLK), BLK, 0, stream>>>(dst, deg, e);
    int nchunks = cdiv(n, 1024);
    scan1_kernel<<<nchunks, 256, 0, stream>>>(deg, row_start, bsums, n);
    scan2_kernel<<<1, 256, 0, stream>>>(bsums, nchunks);
    scan3_kernel<<<cdiv(n, BLK), BLK, 0, stream>>>(deg, row_start, bsums, cursor, inv_deg, n, e);
    scatter_kernel<<<cdiv(e, BLK), BLK, 0, stream>>>(src, dst, cursor, ssrc, e);

    float* out = (float*)d_out;

    // ---- layer 0: 128 -> 64, relu ----  BM=128, TM=8, 256 threads
    lin_tiled4<128, 64, 128, 32, 8, 4, 256><<<cdiv(n, 128), 256, 0, stream>>>(emb, wl0, wr0, b0, Y, xA, n);
    agg4_kernel<64, true><<<cdiv(n * 16, BLK), BLK, 0, stream>>>((const float4*)Y, row_start, ssrc, inv_deg, (float4*)xA, n);

    // ---- layer 1: 64 -> 32, relu ----  BM=64, TM=4, 128 threads
    lin_tiled4<64, 32, 64, 32, 4, 4, 128><<<cdiv(n, 64), 128, 0, stream>>>(xA, wl1, wr1, b1, Y, xB, n);
    agg4_kernel<32, true><<<cdiv(n * 8, BLK), BLK, 0, stream>>>((const float4*)Y, row_start, ssrc, inv_deg, (float4*)xB, n);

    // ---- layer 2: 32 -> 16, relu ----  naive (R1-measured class)
    lin_naive<32, 16><<<cdiv(n * 16, BLK), BLK, 0, stream>>>(xB, wl2, wr2, b2, Y, xA, n);
    agg4_kernel<16, true><<<cdiv(n * 4, BLK), BLK, 0, stream>>>((const float4*)Y, row_start, ssrc, inv_deg, (float4*)xA, n);

    // ---- layer 3: 16 -> 9, no relu ----
    lin_naive<16, 9><<<cdiv(n * 9, BLK), BLK, 0, stream>>>(xA, wl3, wr3, b3, Y, out, n);
    agg_kernel<9, false><<<cdiv(n * 9, BLK), BLK, 0, stream>>>(Y, row_start, ssrc, inv_deg, out, n);
}